// Round 5
// baseline (87.520 us; speedup 1.0000x reference)
//
#include <hip/hip_runtime.h>

// EquivDeepSet: out[b][c][iy][ix], c = {density, f1, f2}
// Separable Gaussian: Gram[g,n] = exp2(s*dx^2)*exp2(s*dy^2), s = -log2e/(2 l^2).
// Block = 64x64 output tile, 256 threads, 4x4 register tile/thread:
//   8 ds_read_b64 serve 32 pair-steps -> LDS 384 cyc/CU vs VALU 512 cyc/CU
//   (VALU-bound, 4 ops/pair floor ~6.8 us).
// Row stride 66 words: Ex b64 read banks = (2*ixl+2k) mod 32 -> 16 lanes cover
// all 32 banks exactly, zero conflicts; Ey reads are 4-distinct/16-way
// broadcast on distinct banks. Split-K x16 over context (512 blocks),
// float4-vectorized combine kernel sums + divides.

#define NCTX 1024
#define NG   128
#define NB   8
#define CH   64            // ctx per chunk staged in LDS
#define STR  66            // row stride in words

template<int NSPLIT>
__global__ __launch_bounds__(256, 2)
void eds_partial(const float* __restrict__ Xc,    // [B][NCTX][2]
                 const float* __restrict__ Yc,    // [B][NCTX][2]
                 const float* __restrict__ gridp, // [NG*NG][2]
                 const float* __restrict__ logl,  // [1]
                 float* __restrict__ part)        // [NSPLIT][NB][3][NG*NG]
{
    constexpr int SC = NCTX / NSPLIT;   // ctx per block
    __shared__ float sEx[64 * STR];
    __shared__ float sEy[64 * STR];

    const int tid  = threadIdx.x;
    const int ixl  = tid & 15;
    const int iyl  = tid >> 4;          // 0..15
    const int lane = tid & 63;
    const int wv   = tid >> 6;          // wave 0..3

    int blk = blockIdx.x;
    const int s    = blk % NSPLIT;  blk /= NSPLIT;
    const int tile = blk & 3;           // 2x2 tiles of 64x64
    const int b    = blk >> 2;
    const int tx0 = (tile & 1) * 64;
    const int ty0 = (tile >> 1) * 64;

    const float ls = fminf(5.0f, fmaxf(-5.0f, logl[0]));
    const float l  = expf(ls);
    const float scale = -0.7213475204444817f / (l * l);   // -log2e/2 / l^2

    float d[16], a[16], c[16];
    #pragma unroll
    for (int i = 0; i < 16; ++i) { d[i] = 0.0f; a[i] = 0.0f; c[i] = 0.0f; }

    for (int ch = 0; ch < SC / CH; ++ch) {
        const int cb = s * SC + ch * CH;
        if (ch) __syncthreads();

        // ---- build: wave wv covers ALL 64 rows (row = lane), ctx [16wv,16wv+16)
        {
            const float gxr = gridp[2 * (tx0 + lane)];             // xs[row]
            const float gyr = gridp[2 * ((ty0 + lane) * NG) + 1];  // ys[row]
            const float* Xp = Xc + ((size_t)b * NCTX + cb + 16 * wv) * 2;
            float xv[16], yv[16];
            #pragma unroll
            for (int t = 0; t < 8; ++t) {          // wave-uniform window
                const float4 p = ((const float4*)Xp)[t];
                xv[2 * t]     = p.x;  yv[2 * t]     = p.y;
                xv[2 * t + 1] = p.z;  yv[2 * t + 1] = p.w;
            }
            float ex[16], ey[16];
            #pragma unroll
            for (int t = 0; t < 16; ++t) {
                const float dx = gxr - xv[t];
                const float dy = gyr - yv[t];
                ex[t] = exp2f(dx * dx * scale);
                ey[t] = exp2f(dy * dy * scale);
            }
            #pragma unroll
            for (int t = 0; t < 4; ++t) {
                *(float4*)&sEx[lane * STR + 16 * wv + 4 * t] =
                    make_float4(ex[4*t], ex[4*t+1], ex[4*t+2], ex[4*t+3]);
                *(float4*)&sEy[lane * STR + 16 * wv + 4 * t] =
                    make_float4(ey[4*t], ey[4*t+1], ey[4*t+2], ey[4*t+3]);
            }
        }
        __syncthreads();

        const float4* yp = (const float4*)(Yc + ((size_t)b * NCTX + cb) * 2);
        const float* exb = &sEx[ixl * STR];
        const float* eyb = &sEy[iyl * STR];

        #pragma unroll 4
        for (int k = 0; k < CH / 2; ++k) {          // 2 ctx per step
            float2 ex[4], ey[4];
            #pragma unroll
            for (int i = 0; i < 4; ++i) ex[i] = *(const float2*)&exb[16 * i * STR + 2 * k];
            #pragma unroll
            for (int j = 0; j < 4; ++j) ey[j] = *(const float2*)&eyb[16 * j * STR + 2 * k];
            const float4 y = yp[k];                 // (y1,y2)[2k], (y1,y2)[2k+1]
            #pragma unroll
            for (int i = 0; i < 4; ++i) {
                #pragma unroll
                for (int j = 0; j < 4; ++j) {
                    const int o = i * 4 + j;
                    float w;
                    w = ex[i].x * ey[j].x;
                    d[o] += w; a[o] = fmaf(w, y.x, a[o]); c[o] = fmaf(w, y.y, c[o]);
                    w = ex[i].y * ey[j].y;
                    d[o] += w; a[o] = fmaf(w, y.z, a[o]); c[o] = fmaf(w, y.w, c[o]);
                }
            }
        }
    }

    const size_t G = (size_t)NG * NG;
    float* P = part + ((size_t)(s * NB + b) * 3) * G;
    #pragma unroll
    for (int i = 0; i < 4; ++i) {
        #pragma unroll
        for (int j = 0; j < 4; ++j) {
            const int o = (ty0 + iyl + 16 * j) * NG + (tx0 + ixl + 16 * i);
            P[        o] = d[i * 4 + j];
            P[G     + o] = a[i * 4 + j];
            P[2 * G + o] = c[i * 4 + j];
        }
    }
}

template<int NSPLIT>
__global__ __launch_bounds__(256)
void eds_combine(const float* __restrict__ part, float* __restrict__ out)
{
    const size_t G = (size_t)NG * NG;
    const int t = blockIdx.x * 256 + threadIdx.x;   // NB*G/4 threads
    const int b = t >> 12;                          // / 4096 (4096 float4 per batch)
    const int o4 = t & 4095;                        // float4 index within batch
    float4 d = make_float4(0.f, 0.f, 0.f, 0.f);
    float4 a1 = d, a2 = d;
    #pragma unroll
    for (int s = 0; s < NSPLIT; ++s) {
        const float4* P = (const float4*)(part + ((size_t)(s * NB + b) * 3) * G);
        const float4 pd = P[o4];
        const float4 p1 = P[G / 4 + o4];
        const float4 p2 = P[G / 2 + o4];
        d.x += pd.x; d.y += pd.y; d.z += pd.z; d.w += pd.w;
        a1.x += p1.x; a1.y += p1.y; a1.z += p1.z; a1.w += p1.w;
        a2.x += p2.x; a2.y += p2.y; a2.z += p2.z; a2.w += p2.w;
    }
    float4* O = (float4*)(out + (size_t)b * 3 * G);
    O[o4] = d;
    O[G / 4 + o4] = make_float4(a1.x / d.x, a1.y / d.y, a1.z / d.z, a1.w / d.w);
    O[G / 2 + o4] = make_float4(a2.x / d.x, a2.y / d.y, a2.z / d.z, a2.w / d.w);
}

extern "C" void kernel_launch(void* const* d_in, const int* in_sizes, int n_in,
                              void* d_out, int out_size, void* d_ws, size_t ws_size,
                              hipStream_t stream) {
    const float* Xc = (const float*)d_in[0];
    const float* Yc = (const float*)d_in[1];
    const float* gr = (const float*)d_in[2];
    const float* ll = (const float*)d_in[3];
    float* out  = (float*)d_out;
    float* part = (float*)d_ws;

    const size_t need16 = (size_t)16 * NB * 3 * NG * NG * sizeof(float);  // 25.2 MB
    if (ws_size >= need16) {
        eds_partial<16><<<dim3(NB * 4 * 16), dim3(256), 0, stream>>>(Xc, Yc, gr, ll, part);
        eds_combine<16><<<dim3(NB * NG * NG / 4 / 256), dim3(256), 0, stream>>>(part, out);
    } else {
        eds_partial<4><<<dim3(NB * 4 * 4), dim3(256), 0, stream>>>(Xc, Yc, gr, ll, part);
        eds_combine<4><<<dim3(NB * NG * NG / 4 / 256), dim3(256), 0, stream>>>(part, out);
    }
}